// Round 4
// baseline (171.518 us; speedup 1.0000x reference)
//
#include <hip/hip_runtime.h>
#include <hip/hip_bf16.h>

#define DIMV 512
#define HDV  64
#define VSTR 514                        // shorts per Vt row (512 + 2 pad)
#define KRING_B 12288                   // 3 x 4096 B K-tile ring
#define VT_BASE KRING_B
#define SMEM_B (VT_BASE + 64 * VSTR * 2)   // 78,080 B -> 2 blocks/CU

typedef __bf16 bf16x8_t __attribute__((ext_vector_type(8)));
typedef float f32x4_t __attribute__((ext_vector_type(4)));

union Frag { bf16x8_t v; unsigned short u[8]; unsigned int w[4]; uint2 d[2]; uint4 q; };

__device__ __forceinline__ unsigned short f2bf(float f) {
  return __builtin_bit_cast(unsigned short, (__bf16)f);
}
__device__ __forceinline__ float bf2f(unsigned int h) {
  return __builtin_bit_cast(float, h << 16);
}

__global__ __launch_bounds__(512, 4)
void lepe_attn_kernel(const float* __restrict__ qkv,
                      const float* __restrict__ lw,
                      const float* __restrict__ lb,
                      float* __restrict__ out)
{
  __shared__ __align__(16) unsigned char smem[SMEM_B];

  const int bidx = blockIdx.x;
  const int qh   = bidx & 1;
  const int head = (bidx >> 1) & 7;
  const int win  = bidx >> 4;
  const int bat  = win >> 3;
  const int nw   = win & 7;

  const int tid  = threadIdx.x;
  const int wave = tid >> 6, lane = tid & 63;
  const int l15  = lane & 15, g = lane >> 4;

  const float* qptr = qkv;
  const float* kptr = qkv + 16777216;
  const float* vptr = qkv + 33554432;
  const int rowbase = bat * 4096;

  auto growf = [&](int tok) -> size_t {
    return ((size_t)(rowbase + ((tok >> 3) << 6) + (nw << 3) + (tok & 7))) * DIMV
           + head * HDV;
  };

  // staging mapping: token s_t (tile-local 0..31), channel quad s_c
  const int s_t = tid >> 4;
  const int s_c = (tid & 15) * 4;
  const size_t TSTRIDE = 131072;   // floats between consecutive 32-token tiles

  const float* kg = kptr + growf(s_t) + s_c;
  const float* vg = vptr + growf(s_t) + s_c;
  const int kwb = s_t * 128 + ((s_c * 2) ^ ((s_t & 7) << 4));   // within-tile byte

  // ---- prologue: issue K tiles 0,1 early; stage Vt under their latency ----
  float4 kA = *(const float4*)kg;                     // tile 0
  float4 kB = *(const float4*)(kg + TSTRIDE);         // tile 1

  unsigned short* vt = (unsigned short*)(smem + VT_BASE);
  #pragma unroll 4
  for (int j = 0; j < 16; ++j) {
    float4 f = *(const float4*)(vg + (size_t)j * TSTRIDE);
    int t = s_t + 32 * j;
    vt[(s_c + 0) * VSTR + t] = f2bf(f.x);
    vt[(s_c + 1) * VSTR + t] = f2bf(f.y);
    vt[(s_c + 2) * VSTR + t] = f2bf(f.z);
    vt[(s_c + 3) * VSTR + t] = f2bf(f.w);
  }

  // ---- Q frags (contiguous k-map: elem j <-> channel kc*32 + 8g + j),
  //      pre-scaled by 0.125*log2(e) so P = exp2(S) ----
  const float QSC = 0.1803368801f;
  const int qbase = qh * 256 + wave * 32;
  Frag qf[2][2];
  #pragma unroll
  for (int qi = 0; qi < 2; ++qi) {
    const float* qp = qptr + growf(qbase + qi * 16 + l15);
    #pragma unroll
    for (int kc = 0; kc < 2; ++kc) {
      float4 f0 = *(const float4*)(qp + kc * 32 + 8 * g);
      float4 f1 = *(const float4*)(qp + kc * 32 + 8 * g + 4);
      qf[qi][kc].u[0] = f2bf(f0.x * QSC); qf[qi][kc].u[1] = f2bf(f0.y * QSC);
      qf[qi][kc].u[2] = f2bf(f0.z * QSC); qf[qi][kc].u[3] = f2bf(f0.w * QSC);
      qf[qi][kc].u[4] = f2bf(f1.x * QSC); qf[qi][kc].u[5] = f2bf(f1.y * QSC);
      qf[qi][kc].u[6] = f2bf(f1.z * QSC); qf[qi][kc].u[7] = f2bf(f1.w * QSC);
    }
  }

  { // write K tile 0 into ring slot 0
    uint2 kp;
    kp.x = (unsigned)f2bf(kA.x) | ((unsigned)f2bf(kA.y) << 16);
    kp.y = (unsigned)f2bf(kA.z) | ((unsigned)f2bf(kA.w) << 16);
    *(uint2*)(smem + kwb) = kp;
  }
  __syncthreads();

  const f32x4_t zero4 = {0.f, 0.f, 0.f, 0.f};
  f32x4_t ot[4][2];
  #pragma unroll
  for (int di = 0; di < 4; ++di)
    #pragma unroll
    for (int qi = 0; qi < 2; ++qi) ot[di][qi] = zero4;
  float lsum[2] = {0.f, 0.f};

  int ro = 0, wo = 4096;   // ring read/write offsets

  // ---- main loop: 16 K-tiles of 32 keys, 3-ring, 2-ahead prefetch ----
  #pragma unroll 2
  for (int kt = 0; kt < 16; ++kt) {
    if (kt < 14) {   // issue load for tile kt+2 (consumed 2 iters later)
      if ((kt & 1) == 0) kA = *(const float4*)(kg + (size_t)(kt + 2) * TSTRIDE);
      else               kB = *(const float4*)(kg + (size_t)(kt + 2) * TSTRIDE);
    }

    const unsigned char* kbR = smem + ro;
    Frag kf[2][2];
    #pragma unroll
    for (int ki = 0; ki < 2; ++ki) {
      int row = ki * 16 + l15;
      const unsigned char* rowp = kbR + row * 128;
      int sw = (row & 7) << 4;
      #pragma unroll
      for (int kc = 0; kc < 2; ++kc)
        kf[ki][kc].q = *(const uint4*)(rowp + ((kc * 64 + g * 16) ^ sw));
    }

    f32x4_t st[2][2];
    #pragma unroll
    for (int ki = 0; ki < 2; ++ki)
      #pragma unroll
      for (int qi = 0; qi < 2; ++qi) st[ki][qi] = zero4;

    __builtin_amdgcn_s_setprio(1);
    #pragma unroll
    for (int kc = 0; kc < 2; ++kc)
      #pragma unroll
      for (int ki = 0; ki < 2; ++ki)
        #pragma unroll
        for (int qi = 0; qi < 2; ++qi)
          st[ki][qi] = __builtin_amdgcn_mfma_f32_16x16x32_bf16(
              kf[ki][kc].v, qf[qi][kc].v, st[ki][qi], 0, 0, 0);
    __builtin_amdgcn_s_setprio(0);

    #pragma unroll
    for (int ki = 0; ki < 2; ++ki)
      #pragma unroll
      for (int qi = 0; qi < 2; ++qi) {
        f32x4_t s = st[ki][qi];
        #pragma unroll
        for (int r = 0; r < 4; ++r) {
          float p = exp2f(s[r]);
          s[r] = p;
          lsum[qi] += p;
        }
        st[ki][qi] = s;
      }

    Frag vf[4];
    #pragma unroll
    for (int di = 0; di < 4; ++di) {
      const unsigned char* p = smem + VT_BASE + (di * 16 + l15) * (VSTR * 2)
                               + kt * 64 + 8 * g;
      vf[di].d[0] = *(const uint2*)(p);
      vf[di].d[1] = *(const uint2*)(p + 32);
    }

    __builtin_amdgcn_s_setprio(1);
    #pragma unroll
    for (int qi = 0; qi < 2; ++qi) {
      Frag pb;
      #pragma unroll
      for (int r = 0; r < 4; ++r) {
        pb.u[r]     = f2bf(st[0][qi][r]);
        pb.u[4 + r] = f2bf(st[1][qi][r]);
      }
      #pragma unroll
      for (int di = 0; di < 4; ++di)
        ot[di][qi] = __builtin_amdgcn_mfma_f32_16x16x32_bf16(
            vf[di].v, pb.v, ot[di][qi], 0, 0, 0);
    }
    __builtin_amdgcn_s_setprio(0);

    if (kt < 15) {   // write tile kt+1 (reg loaded at iter kt-1 / prologue)
      const float4 wv = (kt & 1) ? kA : kB;
      uint2 kp;
      kp.x = (unsigned)f2bf(wv.x) | ((unsigned)f2bf(wv.y) << 16);
      kp.y = (unsigned)f2bf(wv.z) | ((unsigned)f2bf(wv.w) << 16);
      *(uint2*)(smem + wo + kwb) = kp;
      ro = wo;
      wo = (wo == 8192) ? 0 : wo + 4096;
      __syncthreads();
    }
  }

  // ---- softmax denominators ----
  float rl[2];
  #pragma unroll
  for (int qi = 0; qi < 2; ++qi) {
    float s = lsum[qi];
    s += __shfl_xor(s, 16, 64);
    s += __shfl_xor(s, 32, 64);
    rl[qi] = 1.0f / s;
  }

  // ---- LePE conv from Vt LDS (lane = channel) ----
  float wgt[9];
  {
    const float* wp = lw + (size_t)(head * HDV + lane) * 9;
    #pragma unroll
    for (int i = 0; i < 9; ++i) wgt[i] = wp[i];
  }
  const float bias = lb[head * HDV + lane];
  const int yb = qh * 32 + wave * 4;

  float rm[8], rc[8], rp2[8], lout[32];
  auto loadrow = [&](int y, float* dst) {
    if ((unsigned)y < 64u) {
      const unsigned char* p = smem + VT_BASE + lane * (VSTR * 2) + y * 16;
      unsigned a0 = *(const unsigned*)(p);
      unsigned a1 = *(const unsigned*)(p + 4);
      unsigned a2 = *(const unsigned*)(p + 8);
      unsigned a3 = *(const unsigned*)(p + 12);
      dst[0] = bf2f(a0 & 0xffffu); dst[1] = bf2f(a0 >> 16);
      dst[2] = bf2f(a1 & 0xffffu); dst[3] = bf2f(a1 >> 16);
      dst[4] = bf2f(a2 & 0xffffu); dst[5] = bf2f(a2 >> 16);
      dst[6] = bf2f(a3 & 0xffffu); dst[7] = bf2f(a3 >> 16);
    } else {
      #pragma unroll
      for (int x = 0; x < 8; ++x) dst[x] = 0.f;
    }
  };
  loadrow(yb - 1, rm);
  loadrow(yb, rc);
  #pragma unroll
  for (int yy = 0; yy < 4; ++yy) {
    loadrow(yb + yy + 1, rp2);
    #pragma unroll
    for (int x = 0; x < 8; ++x) {
      float acc = bias;
      if (x > 0) acc += rm[x-1]*wgt[0] + rc[x-1]*wgt[3] + rp2[x-1]*wgt[6];
      acc += rm[x]*wgt[1] + rc[x]*wgt[4] + rp2[x]*wgt[7];
      if (x < 7) acc += rm[x+1]*wgt[2] + rc[x+1]*wgt[5] + rp2[x+1]*wgt[8];
      lout[yy * 8 + x] = acc;
    }
    #pragma unroll
    for (int x = 0; x < 8; ++x) { rm[x] = rc[x]; rc[x] = rp2[x]; }
  }

  __syncthreads();   // done reading Vt; reuse LDS for transpose bounce

  unsigned char* bp = smem + wave * 4352;   // [32 tok][68 ch] bf16 per wave
  #pragma unroll
  for (int t = 0; t < 32; ++t)
    *(unsigned short*)(bp + t * 136 + 2 * lane) = f2bf(lout[t]);
  __syncthreads();

  // ---- normalize, add LePE, store ----
  #pragma unroll
  for (int qi = 0; qi < 2; ++qi) {
    const float rlq = rl[qi];
    const int tl = qi * 16 + l15;
    float* op = out + growf(qbase + tl);
    #pragma unroll
    for (int di = 0; di < 4; ++di) {
      uint2 lv = *(const uint2*)(bp + tl * 136 + di * 32 + 8 * g);
      float4 o;
      o.x = ot[di][qi][0] * rlq + bf2f(lv.x & 0xffffu);
      o.y = ot[di][qi][1] * rlq + bf2f(lv.x >> 16);
      o.z = ot[di][qi][2] * rlq + bf2f(lv.y & 0xffffu);
      o.w = ot[di][qi][3] * rlq + bf2f(lv.y >> 16);
      *(float4*)(op + di * 16 + 4 * g) = o;
    }
  }
}

extern "C" void kernel_launch(void* const* d_in, const int* in_sizes, int n_in,
                              void* d_out, int out_size, void* d_ws, size_t ws_size,
                              hipStream_t stream) {
  const float* qkv = (const float*)d_in[0];
  const float* lw  = (const float*)d_in[1];
  const float* lb  = (const float*)d_in[2];
  float* out = (float*)d_out;
  (void)in_sizes; (void)n_in; (void)out_size; (void)d_ws; (void)ws_size;

  dim3 grid(1024);   // 64 win x 8 heads x 2 query-halves
  dim3 block(512);   // 8 waves x 32 queries
  hipLaunchKernelGGL(lepe_attn_kernel, grid, block, 0, stream, qkv, lw, lb, out);
}

// Round 5
// 79.970 us; speedup vs baseline: 2.1448x; 2.1448x over previous
//
#include <hip/hip_runtime.h>
#include <hip/hip_bf16.h>

#define DIMV 512
#define HDV  64
#define VSTR 520                          // shorts per Vt row (512 + 8 pad) -> vf reads 2-way (free)
#define VT_BASE 65536                     // K region: 512 rows x 128 B (XOR-swizzled, no pad)
#define SMEM_B (VT_BASE + 64 * VSTR * 2)  // 132,096 B

typedef __bf16 bf16x8_t __attribute__((ext_vector_type(8)));
typedef float f32x4_t __attribute__((ext_vector_type(4)));

union Frag { bf16x8_t v; unsigned short u[8]; unsigned int w[4]; uint2 d[2]; uint4 q; };

__device__ __forceinline__ unsigned short f2bf(float f) {
  return __builtin_bit_cast(unsigned short, (__bf16)f);
}
__device__ __forceinline__ float bf2f(unsigned int h) {
  return __builtin_bit_cast(float, h << 16);
}

__global__ __launch_bounds__(1024, 1)
void lepe_attn_kernel(const float* __restrict__ qkv,
                      const float* __restrict__ lw,
                      const float* __restrict__ lb,
                      float* __restrict__ out)
{
  __shared__ __align__(16) unsigned char smem[SMEM_B];

  const int head = blockIdx.x & 7;
  const int win  = blockIdx.x >> 3;
  const int bat  = win >> 3;
  const int nw   = win & 7;

  const int tid  = threadIdx.x;
  const int wave = tid >> 6, lane = tid & 63;
  const int l15  = lane & 15, g = lane >> 4;

  const float* qptr = qkv;
  const float* kptr = qkv + 16777216;
  const float* vptr = qkv + 33554432;
  const int rowbase = bat * 4096;

  auto growf = [&](int tok) -> size_t {
    return ((size_t)(rowbase + ((tok >> 3) << 6) + (nw << 3) + (tok & 7))) * DIMV
           + head * HDV;
  };

  // ---- staging mapping: token s_t (0..63 per group), channel quad s_c ----
  const int s_t = tid >> 4;              // 0..63
  const int s_c = (tid & 15) * 4;        // 0..60
  const size_t TSTRIDE = 262144;         // floats between 64-token groups

  const float* kg = kptr + growf(s_t) + s_c;
  const float* vg = vptr + growf(s_t) + s_c;
  const int kwbase = s_t * 128 + ((s_c * 2) ^ ((s_t & 7) << 4));

  // stage K (8 x float4) and Vt (8 x float4) -- all loads issued, then converted
  float4 kin[8], vin[8];
  #pragma unroll
  for (int j = 0; j < 8; ++j) kin[j] = *(const float4*)(kg + (size_t)j * TSTRIDE);
  #pragma unroll
  for (int j = 0; j < 8; ++j) vin[j] = *(const float4*)(vg + (size_t)j * TSTRIDE);

  unsigned short* vt = (unsigned short*)(smem + VT_BASE);
  #pragma unroll
  for (int j = 0; j < 8; ++j) {
    uint2 kp;
    kp.x = (unsigned)f2bf(kin[j].x) | ((unsigned)f2bf(kin[j].y) << 16);
    kp.y = (unsigned)f2bf(kin[j].z) | ((unsigned)f2bf(kin[j].w) << 16);
    *(uint2*)(smem + kwbase + j * 8192) = kp;
    int t = s_t + 64 * j;
    vt[(s_c + 0) * VSTR + t] = f2bf(vin[j].x);
    vt[(s_c + 1) * VSTR + t] = f2bf(vin[j].y);
    vt[(s_c + 2) * VSTR + t] = f2bf(vin[j].z);
    vt[(s_c + 3) * VSTR + t] = f2bf(vin[j].w);
  }

  // ---- Q frags (contiguous k-map), pre-scaled by 0.125*log2(e): P = exp2(S)
  const float QSC = 0.1803368801f;
  const int qbase = wave * 32;
  Frag qf[2][2];
  #pragma unroll
  for (int qi = 0; qi < 2; ++qi) {
    const float* qp = qptr + growf(qbase + qi * 16 + l15);
    #pragma unroll
    for (int kc = 0; kc < 2; ++kc) {
      float4 f0 = *(const float4*)(qp + kc * 32 + 8 * g);
      float4 f1 = *(const float4*)(qp + kc * 32 + 8 * g + 4);
      qf[qi][kc].u[0] = f2bf(f0.x * QSC); qf[qi][kc].u[1] = f2bf(f0.y * QSC);
      qf[qi][kc].u[2] = f2bf(f0.z * QSC); qf[qi][kc].u[3] = f2bf(f0.w * QSC);
      qf[qi][kc].u[4] = f2bf(f1.x * QSC); qf[qi][kc].u[5] = f2bf(f1.y * QSC);
      qf[qi][kc].u[6] = f2bf(f1.z * QSC); qf[qi][kc].u[7] = f2bf(f1.w * QSC);
    }
  }

  __syncthreads();   // the ONLY barrier before the main loop

  const f32x4_t zero4 = {0.f, 0.f, 0.f, 0.f};
  f32x4_t ot[4][2];
  #pragma unroll
  for (int di = 0; di < 4; ++di)
    #pragma unroll
    for (int qi = 0; qi < 2; ++qi) ot[di][qi] = zero4;
  float lsum[2] = {0.f, 0.f};

  // ---- main loop: 16 key tiles of 32, fully resident, NO barriers ----
  const int ksw = (l15 & 7) << 4;
  #pragma unroll 4
  for (int kt = 0; kt < 16; ++kt) {
    Frag kf[2][2];
    #pragma unroll
    for (int ki = 0; ki < 2; ++ki) {
      const unsigned char* rowp = smem + (kt * 32 + ki * 16 + l15) * 128;
      #pragma unroll
      for (int kc = 0; kc < 2; ++kc)
        kf[ki][kc].q = *(const uint4*)(rowp + ((kc * 64 + g * 16) ^ ksw));
    }

    f32x4_t st[2][2];
    #pragma unroll
    for (int ki = 0; ki < 2; ++ki)
      #pragma unroll
      for (int qi = 0; qi < 2; ++qi) st[ki][qi] = zero4;

    __builtin_amdgcn_s_setprio(1);
    #pragma unroll
    for (int kc = 0; kc < 2; ++kc)
      #pragma unroll
      for (int ki = 0; ki < 2; ++ki)
        #pragma unroll
        for (int qi = 0; qi < 2; ++qi)
          st[ki][qi] = __builtin_amdgcn_mfma_f32_16x16x32_bf16(
              kf[ki][kc].v, qf[qi][kc].v, st[ki][qi], 0, 0, 0);
    __builtin_amdgcn_s_setprio(0);

    #pragma unroll
    for (int ki = 0; ki < 2; ++ki)
      #pragma unroll
      for (int qi = 0; qi < 2; ++qi) {
        f32x4_t s = st[ki][qi];
        #pragma unroll
        for (int r = 0; r < 4; ++r) {
          float p = __builtin_amdgcn_exp2f(s[r]);
          s[r] = p;
          lsum[qi] += p;
        }
        st[ki][qi] = s;
      }

    Frag vf[4];
    #pragma unroll
    for (int di = 0; di < 4; ++di) {
      const unsigned char* p = smem + VT_BASE + (di * 16 + l15) * (VSTR * 2)
                               + kt * 64 + 8 * g;
      vf[di].d[0] = *(const uint2*)(p);
      vf[di].d[1] = *(const uint2*)(p + 32);
    }

    __builtin_amdgcn_s_setprio(1);
    #pragma unroll
    for (int qi = 0; qi < 2; ++qi) {
      Frag pb;
      #pragma unroll
      for (int r = 0; r < 4; ++r) {
        pb.u[r]     = f2bf(st[0][qi][r]);
        pb.u[4 + r] = f2bf(st[1][qi][r]);
      }
      #pragma unroll
      for (int di = 0; di < 4; ++di)
        ot[di][qi] = __builtin_amdgcn_mfma_f32_16x16x32_bf16(
            vf[di].v, pb.v, ot[di][qi], 0, 0, 0);
    }
    __builtin_amdgcn_s_setprio(0);
  }

  // ---- softmax denominators ----
  float rl[2];
  #pragma unroll
  for (int qi = 0; qi < 2; ++qi) {
    float s = lsum[qi];
    s += __shfl_xor(s, 16, 64);
    s += __shfl_xor(s, 32, 64);
    rl[qi] = 1.0f / s;
  }

  // ---- LePE conv from Vt LDS (lane = channel), wave handles rows wave*4..+3
  float wgt[9];
  {
    const float* wp = lw + (size_t)(head * HDV + lane) * 9;
    #pragma unroll
    for (int i = 0; i < 9; ++i) wgt[i] = wp[i];
  }
  const float bias = lb[head * HDV + lane];
  const int yb = wave * 4;

  float rm[8], rc[8], rp2[8], lout[32];
  auto loadrow = [&](int y, float* dst) {
    if ((unsigned)y < 64u) {
      const unsigned char* p = smem + VT_BASE + lane * (VSTR * 2) + y * 16;
      unsigned a0 = *(const unsigned*)(p);
      unsigned a1 = *(const unsigned*)(p + 4);
      unsigned a2 = *(const unsigned*)(p + 8);
      unsigned a3 = *(const unsigned*)(p + 12);
      dst[0] = bf2f(a0 & 0xffffu); dst[1] = bf2f(a0 >> 16);
      dst[2] = bf2f(a1 & 0xffffu); dst[3] = bf2f(a1 >> 16);
      dst[4] = bf2f(a2 & 0xffffu); dst[5] = bf2f(a2 >> 16);
      dst[6] = bf2f(a3 & 0xffffu); dst[7] = bf2f(a3 >> 16);
    } else {
      #pragma unroll
      for (int x = 0; x < 8; ++x) dst[x] = 0.f;
    }
  };
  loadrow(yb - 1, rm);
  loadrow(yb, rc);
  #pragma unroll
  for (int yy = 0; yy < 4; ++yy) {
    loadrow(yb + yy + 1, rp2);
    #pragma unroll
    for (int x = 0; x < 8; ++x) {
      float acc = bias;
      if (x > 0) acc += rm[x-1]*wgt[0] + rc[x-1]*wgt[3] + rp2[x-1]*wgt[6];
      acc += rm[x]*wgt[1] + rc[x]*wgt[4] + rp2[x]*wgt[7];
      if (x < 7) acc += rm[x+1]*wgt[2] + rc[x+1]*wgt[5] + rp2[x+1]*wgt[8];
      lout[yy * 8 + x] = acc;
    }
    #pragma unroll
    for (int x = 0; x < 8; ++x) { rm[x] = rc[x]; rc[x] = rp2[x]; }
  }

  __syncthreads();   // all waves done reading Vt; reuse LDS for transpose bounce

  unsigned char* bp = smem + wave * 4352;   // [32 tok][68 ch] bf16 per wave
  #pragma unroll
  for (int t = 0; t < 32; ++t)
    *(unsigned short*)(bp + t * 136 + 2 * lane) = f2bf(lout[t]);
  __syncthreads();

  // ---- normalize, add LePE, store ----
  #pragma unroll
  for (int qi = 0; qi < 2; ++qi) {
    const float rlq = rl[qi];
    const int tl = qi * 16 + l15;
    float* op = out + growf(qbase + tl);
    #pragma unroll
    for (int di = 0; di < 4; ++di) {
      uint2 lv = *(const uint2*)(bp + tl * 136 + di * 32 + 8 * g);
      float4 o;
      o.x = ot[di][qi][0] * rlq + bf2f(lv.x & 0xffffu);
      o.y = ot[di][qi][1] * rlq + bf2f(lv.x >> 16);
      o.z = ot[di][qi][2] * rlq + bf2f(lv.y & 0xffffu);
      o.w = ot[di][qi][3] * rlq + bf2f(lv.y >> 16);
      *(float4*)(op + di * 16 + 4 * g) = o;
    }
  }
}

extern "C" void kernel_launch(void* const* d_in, const int* in_sizes, int n_in,
                              void* d_out, int out_size, void* d_ws, size_t ws_size,
                              hipStream_t stream) {
  const float* qkv = (const float*)d_in[0];
  const float* lw  = (const float*)d_in[1];
  const float* lb  = (const float*)d_in[2];
  float* out = (float*)d_out;
  (void)in_sizes; (void)n_in; (void)out_size; (void)d_ws; (void)ws_size;

  dim3 grid(512);    // 64 win x 8 heads
  dim3 block(1024);  // 16 waves x 32 queries
  hipLaunchKernelGGL(lepe_attn_kernel, grid, block, 0, stream, qkv, lw, lb, out);
}

// Round 6
// 78.450 us; speedup vs baseline: 2.1863x; 1.0194x over previous
//
#include <hip/hip_runtime.h>
#include <hip/hip_bf16.h>

#define DIMV 512
#define HDV  64
#define VSTR 524                          // shorts per Vt row: 1048 B = 6 dwords mod 32 banks
                                          // -> vf reads conflict-free, LePE/staging 4-way
#define VT_BASE 65536                     // K region: 512 rows x 128 B (XOR-swizzled)
#define SMEM_B (VT_BASE + 64 * VSTR * 2)  // 132,608 B

typedef __bf16 bf16x8_t __attribute__((ext_vector_type(8)));
typedef float f32x4_t __attribute__((ext_vector_type(4)));

union Frag { bf16x8_t v; unsigned short u[8]; unsigned int w[4]; uint2 d[2]; uint4 q; };

__device__ __forceinline__ unsigned short f2bf(float f) {
  return __builtin_bit_cast(unsigned short, (__bf16)f);
}
__device__ __forceinline__ float bf2f(unsigned int h) {
  return __builtin_bit_cast(float, h << 16);
}

// Barrier that does NOT drain vmcnt: LDS-write visibility only. Outstanding
// global loads (into private carrier regs) stay in flight across it.
#define BARRIER_NODRAIN() asm volatile("s_waitcnt lgkmcnt(0)\n\ts_barrier" ::: "memory")

__global__ __launch_bounds__(1024, 4)
void lepe_attn_kernel(const float* __restrict__ qkv,
                      const float* __restrict__ lw,
                      const float* __restrict__ lb,
                      float* __restrict__ out)
{
  __shared__ __align__(16) unsigned char smem[SMEM_B];

  const int head = blockIdx.x & 7;
  const int win  = blockIdx.x >> 3;
  const int bat  = win >> 3;
  const int nw   = win & 7;

  const int tid  = threadIdx.x;
  const int wave = tid >> 6, lane = tid & 63;
  const int l15  = lane & 15, g = lane >> 4;

  const float* qptr = qkv;
  const float* kptr = qkv + 16777216;
  const float* vptr = qkv + 33554432;
  const int rowbase = bat * 4096;

  auto growf = [&](int tok) -> size_t {
    return ((size_t)(rowbase + ((tok >> 3) << 6) + (nw << 3) + (tok & 7))) * DIMV
           + head * HDV;
  };

  // ---- staging mapping: token s_t (0..63 within group), channel quad s_c ----
  const int s_t = tid >> 4;              // 0..63
  const int s_c = (tid & 15) * 4;        // 0..60
  const size_t TSTRIDE = 262144;         // floats between 64-token groups
  // chunk c = groups {2c, 2c+1} = tokens 128c .. 128c+127

  const float* kg = kptr + growf(s_t) + s_c;
  const float* vg = vptr + growf(s_t) + s_c;
  const int kwbase = s_t * 128 + ((s_c * 2) ^ ((s_t & 7) << 4));
  unsigned short* vt = (unsigned short*)(smem + VT_BASE);

  float4 ck0, ck1, cv0, cv1;   // carrier: one chunk (2 groups of K + V)

  auto issue_chunk = [&](int c) {
    ck0 = *(const float4*)(kg + (size_t)(2 * c) * TSTRIDE);
    ck1 = *(const float4*)(kg + (size_t)(2 * c + 1) * TSTRIDE);
    cv0 = *(const float4*)(vg + (size_t)(2 * c) * TSTRIDE);
    cv1 = *(const float4*)(vg + (size_t)(2 * c + 1) * TSTRIDE);
  };
  auto write_chunk = [&](int c) {
    uint2 kp;
    kp.x = (unsigned)f2bf(ck0.x) | ((unsigned)f2bf(ck0.y) << 16);
    kp.y = (unsigned)f2bf(ck0.z) | ((unsigned)f2bf(ck0.w) << 16);
    *(uint2*)(smem + kwbase + (2 * c) * 8192) = kp;
    kp.x = (unsigned)f2bf(ck1.x) | ((unsigned)f2bf(ck1.y) << 16);
    kp.y = (unsigned)f2bf(ck1.z) | ((unsigned)f2bf(ck1.w) << 16);
    *(uint2*)(smem + kwbase + (2 * c + 1) * 8192) = kp;
    int t0 = s_t + 64 * (2 * c);
    vt[(s_c + 0) * VSTR + t0] = f2bf(cv0.x);
    vt[(s_c + 1) * VSTR + t0] = f2bf(cv0.y);
    vt[(s_c + 2) * VSTR + t0] = f2bf(cv0.z);
    vt[(s_c + 3) * VSTR + t0] = f2bf(cv0.w);
    int t1 = t0 + 64;
    vt[(s_c + 0) * VSTR + t1] = f2bf(cv1.x);
    vt[(s_c + 1) * VSTR + t1] = f2bf(cv1.y);
    vt[(s_c + 2) * VSTR + t1] = f2bf(cv1.z);
    vt[(s_c + 3) * VSTR + t1] = f2bf(cv1.w);
  };

  // ---- prologue: chunk 0 + Q loads in flight; write chunk 0; barrier ----
  issue_chunk(0);

  const int qbase = wave * 32;
  float4 qin[8];
  #pragma unroll
  for (int qi = 0; qi < 2; ++qi) {
    const float* qp = qptr + growf(qbase + qi * 16 + l15);
    #pragma unroll
    for (int kc = 0; kc < 2; ++kc) {
      qin[qi * 4 + kc * 2 + 0] = *(const float4*)(qp + kc * 32 + 8 * g);
      qin[qi * 4 + kc * 2 + 1] = *(const float4*)(qp + kc * 32 + 8 * g + 4);
    }
  }

  write_chunk(0);
  BARRIER_NODRAIN();

  // ---- Q frags (contiguous k-map), pre-scaled by 0.125*log2(e): P = exp2(S)
  const float QSC = 0.1803368801f;
  Frag qf[2][2];
  #pragma unroll
  for (int qi = 0; qi < 2; ++qi)
    #pragma unroll
    for (int kc = 0; kc < 2; ++kc) {
      const float4 f0 = qin[qi * 4 + kc * 2 + 0];
      const float4 f1 = qin[qi * 4 + kc * 2 + 1];
      qf[qi][kc].u[0] = f2bf(f0.x * QSC); qf[qi][kc].u[1] = f2bf(f0.y * QSC);
      qf[qi][kc].u[2] = f2bf(f0.z * QSC); qf[qi][kc].u[3] = f2bf(f0.w * QSC);
      qf[qi][kc].u[4] = f2bf(f1.x * QSC); qf[qi][kc].u[5] = f2bf(f1.y * QSC);
      qf[qi][kc].u[6] = f2bf(f1.z * QSC); qf[qi][kc].u[7] = f2bf(f1.w * QSC);
    }

  const f32x4_t zero4 = {0.f, 0.f, 0.f, 0.f};
  f32x4_t ot[4][2];
  #pragma unroll
  for (int di = 0; di < 4; ++di)
    #pragma unroll
    for (int qi = 0; qi < 2; ++qi) ot[di][qi] = zero4;
  float lsum[2] = {0.f, 0.f};

  // ---- main loop: 4 chunks x 4 tiles of 32 keys; 1-ahead chunk pipeline ----
  const int ksw = (l15 & 7) << 4;
  #pragma unroll
  for (int c = 0; c < 4; ++c) {
    if (c < 3) issue_chunk(c + 1);     // in flight across this chunk's compute

    #pragma unroll
    for (int t4 = 0; t4 < 4; ++t4) {
      const int kt = c * 4 + t4;

      Frag kf[2][2];
      #pragma unroll
      for (int ki = 0; ki < 2; ++ki) {
        const unsigned char* rowp = smem + (kt * 32 + ki * 16 + l15) * 128;
        #pragma unroll
        for (int kc = 0; kc < 2; ++kc)
          kf[ki][kc].q = *(const uint4*)(rowp + ((kc * 64 + g * 16) ^ ksw));
      }

      f32x4_t st[2][2];
      #pragma unroll
      for (int ki = 0; ki < 2; ++ki)
        #pragma unroll
        for (int qi = 0; qi < 2; ++qi) st[ki][qi] = zero4;

      __builtin_amdgcn_s_setprio(1);
      #pragma unroll
      for (int kc = 0; kc < 2; ++kc)
        #pragma unroll
        for (int ki = 0; ki < 2; ++ki)
          #pragma unroll
          for (int qi = 0; qi < 2; ++qi)
            st[ki][qi] = __builtin_amdgcn_mfma_f32_16x16x32_bf16(
                kf[ki][kc].v, qf[qi][kc].v, st[ki][qi], 0, 0, 0);
      __builtin_amdgcn_s_setprio(0);

      #pragma unroll
      for (int ki = 0; ki < 2; ++ki)
        #pragma unroll
        for (int qi = 0; qi < 2; ++qi) {
          f32x4_t s = st[ki][qi];
          #pragma unroll
          for (int r = 0; r < 4; ++r) {
            float p = __builtin_amdgcn_exp2f(s[r]);
            s[r] = p;
            lsum[qi] += p;
          }
          st[ki][qi] = s;
        }

      Frag vf[4];
      #pragma unroll
      for (int di = 0; di < 4; ++di) {
        const unsigned char* p = smem + VT_BASE + (di * 16 + l15) * (VSTR * 2)
                                 + kt * 64 + 8 * g;
        vf[di].d[0] = *(const uint2*)(p);
        vf[di].d[1] = *(const uint2*)(p + 32);
      }

      __builtin_amdgcn_s_setprio(1);
      #pragma unroll
      for (int qi = 0; qi < 2; ++qi) {
        Frag pb;
        #pragma unroll
        for (int r = 0; r < 4; ++r) {
          pb.u[r]     = f2bf(st[0][qi][r]);
          pb.u[4 + r] = f2bf(st[1][qi][r]);
        }
        #pragma unroll
        for (int di = 0; di < 4; ++di)
          ot[di][qi] = __builtin_amdgcn_mfma_f32_16x16x32_bf16(
              vf[di].v, pb.v, ot[di][qi], 0, 0, 0);
      }
      __builtin_amdgcn_s_setprio(0);
    }

    if (c < 3) {
      write_chunk(c + 1);      // compiler waits vmcnt for the carrier here
      BARRIER_NODRAIN();       // LDS visibility only; vmcnt NOT drained
    }
  }

  // ---- softmax denominators ----
  float rl[2];
  #pragma unroll
  for (int qi = 0; qi < 2; ++qi) {
    float s = lsum[qi];
    s += __shfl_xor(s, 16, 64);
    s += __shfl_xor(s, 32, 64);
    rl[qi] = 1.0f / s;
  }

  // ---- LePE conv from Vt LDS (lane = channel), wave handles rows wave*4..+3
  float wgt[9];
  {
    const float* wp = lw + (size_t)(head * HDV + lane) * 9;
    #pragma unroll
    for (int i = 0; i < 9; ++i) wgt[i] = wp[i];
  }
  const float bias = lb[head * HDV + lane];
  const int yb = wave * 4;

  float rm[8], rc[8], rp2[8], lout[32];
  auto loadrow = [&](int y, float* dst) {
    if ((unsigned)y < 64u) {
      const unsigned char* p = smem + VT_BASE + lane * (VSTR * 2) + y * 16;
      unsigned a0 = *(const unsigned*)(p);
      unsigned a1 = *(const unsigned*)(p + 4);
      unsigned a2 = *(const unsigned*)(p + 8);
      unsigned a3 = *(const unsigned*)(p + 12);
      dst[0] = bf2f(a0 & 0xffffu); dst[1] = bf2f(a0 >> 16);
      dst[2] = bf2f(a1 & 0xffffu); dst[3] = bf2f(a1 >> 16);
      dst[4] = bf2f(a2 & 0xffffu); dst[5] = bf2f(a2 >> 16);
      dst[6] = bf2f(a3 & 0xffffu); dst[7] = bf2f(a3 >> 16);
    } else {
      #pragma unroll
      for (int x = 0; x < 8; ++x) dst[x] = 0.f;
    }
  };
  loadrow(yb - 1, rm);
  loadrow(yb, rc);
  #pragma unroll
  for (int yy = 0; yy < 4; ++yy) {
    loadrow(yb + yy + 1, rp2);
    #pragma unroll
    for (int x = 0; x < 8; ++x) {
      float acc = bias;
      if (x > 0) acc += rm[x-1]*wgt[0] + rc[x-1]*wgt[3] + rp2[x-1]*wgt[6];
      acc += rm[x]*wgt[1] + rc[x]*wgt[4] + rp2[x]*wgt[7];
      if (x < 7) acc += rm[x+1]*wgt[2] + rc[x+1]*wgt[5] + rp2[x+1]*wgt[8];
      lout[yy * 8 + x] = acc;
    }
    #pragma unroll
    for (int x = 0; x < 8; ++x) { rm[x] = rc[x]; rc[x] = rp2[x]; }
  }

  __syncthreads();   // all waves done with K/Vt; reuse LDS for transpose bounce

  unsigned char* bp = smem + wave * 4352;   // [32 tok][68 ch] bf16 per wave
  #pragma unroll
  for (int t = 0; t < 32; ++t)
    *(unsigned short*)(bp + t * 136 + 2 * lane) = f2bf(lout[t]);
  __syncthreads();

  // ---- normalize, add LePE, store ----
  #pragma unroll
  for (int qi = 0; qi < 2; ++qi) {
    const float rlq = rl[qi];
    const int tl = qi * 16 + l15;
    float* op = out + growf(qbase + tl);
    #pragma unroll
    for (int di = 0; di < 4; ++di) {
      uint2 lv = *(const uint2*)(bp + tl * 136 + di * 32 + 8 * g);
      float4 o;
      o.x = ot[di][qi][0] * rlq + bf2f(lv.x & 0xffffu);
      o.y = ot[di][qi][1] * rlq + bf2f(lv.x >> 16);
      o.z = ot[di][qi][2] * rlq + bf2f(lv.y & 0xffffu);
      o.w = ot[di][qi][3] * rlq + bf2f(lv.y >> 16);
      *(float4*)(op + di * 16 + 4 * g) = o;
    }
  }
}

extern "C" void kernel_launch(void* const* d_in, const int* in_sizes, int n_in,
                              void* d_out, int out_size, void* d_ws, size_t ws_size,
                              hipStream_t stream) {
  const float* qkv = (const float*)d_in[0];
  const float* lw  = (const float*)d_in[1];
  const float* lb  = (const float*)d_in[2];
  float* out = (float*)d_out;
  (void)in_sizes; (void)n_in; (void)out_size; (void)d_ws; (void)ws_size;

  dim3 grid(512);    // 64 win x 8 heads
  dim3 block(1024);  // 16 waves x 32 queries
  hipLaunchKernelGGL(lepe_attn_kernel, grid, block, 0, stream, qkv, lw, lb, out);
}